// Round 2
// baseline (189.857 us; speedup 1.0000x reference)
//
#include <hip/hip_runtime.h>
#include <math.h>

#define N_TRIAL 1000000
#define N_REF 8
#define N_DIM 16
#define BETA 1.0f
#define GAMMA 0.001f
// N_SELECT = {1,2,3,1} packed as nibbles: idx 0->1, 1->2, 2->3, 3->1
#define N_SELECT_PACKED 0x1321

typedef float v4f __attribute__((ext_vector_type(4)));

__device__ __forceinline__ float wdist4(v4f w, v4f a, v4f b) {
    v4f d = a - b;
    v4f p = w * d * d;
    return p.x + p.y + p.z + p.w;
}

__global__ __launch_bounds__(256, 2) void likelihood_kernel(
    const int* __restrict__ stim,     // N_TRIAL x (N_REF+1)
    const int* __restrict__ config,   // N_TRIAL
    const int* __restrict__ group,    // N_TRIAL
    const int* __restrict__ present,  // N_TRIAL x (N_REF+1)
    const float* __restrict__ embed,  // N_STIM x N_DIM
    const float* __restrict__ attw,   // N_GROUP x N_DIM
    float* __restrict__ out)          // N_TRIAL
{
    int t = blockIdx.x * blockDim.x + threadIdx.x;
    if (t >= N_TRIAL) return;

    const int* sp = stim + t * (N_REF + 1);
    const int* pp = present + t * (N_REF + 1);

    // ---- Phase 1: issue ALL independent streaming loads (nontemporal) ----
    int s[N_REF + 1];
#pragma unroll
    for (int i = 0; i < N_REF + 1; ++i)
        s[i] = __builtin_nontemporal_load(sp + i);

    int pr[N_REF];
#pragma unroll
    for (int r = 0; r < N_REF; ++r)
        pr[r] = __builtin_nontemporal_load(pp + 1 + r);

    int g = __builtin_nontemporal_load(group + t);
    int c = __builtin_nontemporal_load(config + t);

    // ---- Phase 2: issue ALL gathers (cached; embed/attw stay L2-resident) ----
    const v4f* wp = (const v4f*)(attw + g * N_DIM);
    v4f w0 = wp[0], w1 = wp[1], w2 = wp[2], w3 = wp[3];

    const v4f* zq = (const v4f*)(embed + s[0] * N_DIM);
    v4f q0 = zq[0], q1 = zq[1], q2 = zq[2], q3 = zq[3];

    v4f R[N_REF][4];
#pragma unroll
    for (int r = 0; r < N_REF; ++r) {
        const v4f* zr = (const v4f*)(embed + s[1 + r] * N_DIM);
        R[r][0] = zr[0];
        R[r][1] = zr[1];
        R[r][2] = zr[2];
        R[r][3] = zr[3];
    }

    // ---- Phase 3: compute (loads drain in order while we consume) ----
    float sim[N_REF];
#pragma unroll
    for (int r = 0; r < N_REF; ++r) {
        float d = wdist4(w0, q0, R[r][0]) + wdist4(w1, q1, R[r][1]) +
                  wdist4(w2, q2, R[r][2]) + wdist4(w3, q3, R[r][3]);
        d = sqrtf(d);
        float s_qr = __expf(-BETA * d) + GAMMA;
        sim[r] = s_qr * (float)pr[r];
    }

    // reverse (suffix) cumulative sum
    float suffix[N_REF];
    float acc = 0.0f;
#pragma unroll
    for (int r = N_REF - 1; r >= 0; --r) {
        acc += sim[r];
        suffix[r] = acc;
    }

    int ns = (N_SELECT_PACKED >> ((c & 3) * 4)) & 0xF;

    // product over masked positions (ns in {1,2,3}; predicated, no divergence)
    float lik = 1.0f;
#pragma unroll
    for (int r = 0; r < N_REF; ++r) {
        lik *= (r < ns) ? (sim[r] / suffix[r]) : 1.0f;
    }

    __builtin_nontemporal_store(lik, out + t);
}

extern "C" void kernel_launch(void* const* d_in, const int* in_sizes, int n_in,
                              void* d_out, int out_size, void* d_ws, size_t ws_size,
                              hipStream_t stream) {
    const int*   stim    = (const int*)d_in[0];
    const int*   config  = (const int*)d_in[1];
    const int*   group   = (const int*)d_in[2];
    const int*   present = (const int*)d_in[3];
    const float* embed   = (const float*)d_in[4];
    const float* attw    = (const float*)d_in[5];
    float*       out     = (float*)d_out;

    int blocks = (N_TRIAL + 255) / 256;
    likelihood_kernel<<<blocks, 256, 0, stream>>>(stim, config, group, present,
                                                  embed, attw, out);
}

// Round 3
// 151.317 us; speedup vs baseline: 1.2547x; 1.2547x over previous
//
#include <hip/hip_runtime.h>
#include <math.h>

#define N_TRIAL 1000000
#define N_REF 8
#define N_DIM 16
#define N_GROUP 4
#define BETA 1.0f
#define GAMMA 0.001f
// N_SELECT = {1,2,3,1} packed as nibbles: idx 0->1, 1->2, 2->3, 3->1
#define N_SELECT_PACKED 0x1321

typedef float v4f __attribute__((ext_vector_type(4)));

// Layout: 4 consecutive lanes ("quad") process one trial. Lane k of the quad
// loads float4 segment k of each 16-float embed row, so one gather instruction
// covers 16 full rows with 16 distinct 64-B cache lines (vs 64 lines for the
// thread-per-trial layout) -- 4x fewer TA line transactions, which is the
// measured per-CU bottleneck (~0.6 lines/cyc/CU in rounds 1-2).
__global__ __launch_bounds__(256) void likelihood_kernel(
    const int* __restrict__ stim,     // N_TRIAL x (N_REF+1)
    const int* __restrict__ config,   // N_TRIAL
    const int* __restrict__ group,    // N_TRIAL
    const int* __restrict__ present,  // N_TRIAL x (N_REF+1)
    const float* __restrict__ embed,  // N_STIM x N_DIM
    const float* __restrict__ attw,   // N_GROUP x N_DIM
    float* __restrict__ out)          // N_TRIAL
{
    __shared__ float s_attw[N_GROUP * N_DIM];  // 256 B

    int tid = threadIdx.x;
    if (tid < N_GROUP * N_DIM) s_attw[tid] = attw[tid];
    __syncthreads();

    int gtid  = blockIdx.x * 256 + tid;       // grid exactly covers 4*N_TRIAL
    int trial = gtid >> 2;
    int seg   = gtid & 3;                     // which float4 of the 16-dim row

    const int* sp = stim + trial * (N_REF + 1);
    const int* pp = present + trial * (N_REF + 1);

    // indices (broadcast across the quad; coalesces to ~9 lines per 16 trials)
    int idx[N_REF + 1];
#pragma unroll
    for (int i = 0; i <= N_REF; ++i) idx[i] = sp[i];

    // gathers: one float4 segment of each of the 9 rows
    v4f z[N_REF + 1];
#pragma unroll
    for (int i = 0; i <= N_REF; ++i)
        z[i] = ((const v4f*)(embed + idx[i] * N_DIM))[seg];

    int pr[N_REF];
#pragma unroll
    for (int r = 0; r < N_REF; ++r) pr[r] = pp[1 + r];

    int g = group[trial];
    int c = config[trial];

    v4f w = ((const v4f*)(s_attw + g * N_DIM))[seg];
    v4f q = z[0];

    float sim[N_REF];
#pragma unroll
    for (int r = 0; r < N_REF; ++r) {
        v4f dd = q - z[1 + r];
        v4f p  = w * dd * dd;
        float d2 = (p.x + p.y) + (p.z + p.w);
        // quad butterfly: full 16-dim sum lands in all 4 lanes
        d2 += __shfl_xor(d2, 1);
        d2 += __shfl_xor(d2, 2);
        float d = sqrtf(d2);
        sim[r] = (__expf(-BETA * d) + GAMMA) * (float)pr[r];
    }

    // reverse (suffix) cumulative sum -- replicated in all 4 lanes (cheap VALU)
    float suffix[N_REF];
    float acc = 0.0f;
#pragma unroll
    for (int r = N_REF - 1; r >= 0; --r) {
        acc += sim[r];
        suffix[r] = acc;
    }

    int ns = (N_SELECT_PACKED >> ((c & 3) * 4)) & 0xF;

    float lik = 1.0f;
#pragma unroll
    for (int r = 0; r < N_REF; ++r) {
        lik *= (r < ns) ? __fdividef(sim[r], suffix[r]) : 1.0f;
    }

    if (seg == 0) out[trial] = lik;   // lanes 0,4,8,...: 16 floats -> 1 line/wave
}

extern "C" void kernel_launch(void* const* d_in, const int* in_sizes, int n_in,
                              void* d_out, int out_size, void* d_ws, size_t ws_size,
                              hipStream_t stream) {
    const int*   stim    = (const int*)d_in[0];
    const int*   config  = (const int*)d_in[1];
    const int*   group   = (const int*)d_in[2];
    const int*   present = (const int*)d_in[3];
    const float* embed   = (const float*)d_in[4];
    const float* attw    = (const float*)d_in[5];
    float*       out     = (float*)d_out;

    // 4 threads per trial; 4e6 / 256 = 15625 blocks exactly, no bounds check
    int blocks = (N_TRIAL * 4) / 256;
    likelihood_kernel<<<blocks, 256, 0, stream>>>(stim, config, group, present,
                                                  embed, attw, out);
}